// Round 7
// baseline (234.791 us; speedup 1.0000x reference)
//
#include <hip/hip_runtime.h>
#include <hip/hip_fp16.h>

// SAGEConv: agg = segment_sum(x[src]*w, dst); out = agg@W_l + b_l + x@W_r + b_r;
// out /= max(sum|out|, 1e-12) row-wise.  N=100000, E=1600000, D=128.
//
// R7: (1) gather v3 - 32 lanes/row (8B fp16 / 16B fp32 per-lane loads),
//     2 edges per step via lane>>5, unroll 4 => 8 edges in flight; scalar
//     edge-metadata loads. (2) sort chain made two-pass deterministic:
//     coarse_count stashes per-block hists; coarse_scan2 computes absolute
//     per-(block,bucket) bases; coarse_partition drops its hist pass and
//     all global cursor atomics.

static constexpr int D = 128;
static constexpr int NB = 1024;     // coarse buckets
static constexpr int CBITS = 7;     // nodes per bucket = 128
static constexpr int CSZ = 1 << CBITS;
static constexpr int NPART = 256;   // partition blocks

typedef _Float16 half8 __attribute__((ext_vector_type(8)));
typedef float f32x4 __attribute__((ext_vector_type(4)));

// ---------------- x -> fp16 staging ----------------
__global__ __launch_bounds__(256) void cvt_x_fp16(
    const float4* __restrict__ x4, __half2* __restrict__ xh2, int n4)
{
    int i = blockIdx.x * blockDim.x + threadIdx.x;
    int stride = gridDim.x * blockDim.x;
    for (; i < n4; i += stride) {
        float4 v = x4[i];
        xh2[2 * i + 0] = __floats2half2_rn(v.x, v.y);
        xh2[2 * i + 1] = __floats2half2_rn(v.z, v.w);
    }
}

// ---------------- W pre-transpose: WT[c][k] fp16, k<128 -> Wl, else Wr ----
__global__ __launch_bounds__(256) void wt_build(
    const float* __restrict__ Wl, const float* __restrict__ Wr,
    __half* __restrict__ wt)
{
    const int idx = blockIdx.x * blockDim.x + threadIdx.x;  // 128 blocks x 256
    if (idx >= 128 * 256) return;
    const int c = idx >> 8;
    const int k = idx & 255;
    const float v = (k < 128) ? Wl[(size_t)k * D + c] : Wr[(size_t)(k - 128) * D + c];
    wt[(size_t)c * 256 + k] = __float2half(v);
}

// ---------------- two-level counting sort (deterministic bases) ----------
__global__ __launch_bounds__(256) void coarse_count(
    const int* __restrict__ edst, int* __restrict__ bhist, int E, int chunk)
{
    __shared__ int hist[NB];
    for (int t = threadIdx.x; t < NB; t += 256) hist[t] = 0;
    __syncthreads();
    const int beg = blockIdx.x * chunk;
    const int end = min(E, beg + chunk);
    for (int e = beg + threadIdx.x; e < end; e += 256)
        atomicAdd(&hist[edst[e] >> CBITS], 1);
    __syncthreads();
    for (int t = threadIdx.x; t < NB; t += 256)
        bhist[(size_t)blockIdx.x * NB + t] = hist[t];
}

// 1 block x NB threads: per-bucket scan over blocks + bucket scan.
// bhist: in = per-block counts, out = absolute per-(block,bucket) bases.
__global__ __launch_bounds__(NB) void coarse_scan2(
    int* __restrict__ bhist, int* __restrict__ cbase,
    int* __restrict__ offs, int N, int E, int nparts)
{
    __shared__ int s[NB];
    const int t = threadIdx.x;
    int run = 0;
    for (int b = 0; b < nparts; ++b) {
        const int v = bhist[(size_t)b * NB + t];
        bhist[(size_t)b * NB + t] = run;   // relative base
        run += v;
    }
    s[t] = run;                             // bucket total
    __syncthreads();
    const int own = run;
    for (int off = 1; off < NB; off <<= 1) {
        const int u = (t >= off) ? s[t - off] : 0;
        __syncthreads();
        s[t] += u;
        __syncthreads();
    }
    const int excl = s[t] - own;
    cbase[t] = excl;
    if (t == NB - 1) { cbase[NB] = s[t]; offs[N] = E; }
    for (int b = 0; b < nparts; ++b)
        bhist[(size_t)b * NB + t] += excl;  // absolute base
}

// partition edges into coarse buckets; pair = (dst_low7<<20 | src, w_bits)
__global__ __launch_bounds__(256) void coarse_partition(
    const int* __restrict__ esrc, const int* __restrict__ edst,
    const float* __restrict__ ew, const int* __restrict__ bhist,
    int2* __restrict__ cpairs, int E, int chunk)
{
    __shared__ int cur[NB];
    for (int t = threadIdx.x; t < NB; t += 256)
        cur[t] = bhist[(size_t)blockIdx.x * NB + t];
    __syncthreads();
    const int beg = blockIdx.x * chunk;
    const int end = min(E, beg + chunk);
    for (int e = beg + threadIdx.x; e < end; e += 256) {
        const int d = edst[e];
        const int pos = atomicAdd(&cur[d >> CBITS], 1);
        cpairs[pos] = make_int2(((d & (CSZ - 1)) << 20) | esrc[e],
                                __float_as_int(ew[e]));
    }
}

// one block per coarse bucket: fine 128-bin counting sort + offs[] write
__global__ __launch_bounds__(256) void fine_sort(
    const int2* __restrict__ cpairs, const int* __restrict__ cbase,
    int* __restrict__ offs, int2* __restrict__ pairs, int N)
{
    __shared__ int hist[CSZ];
    __shared__ int scn[CSZ];
    const int b = blockIdx.x;
    const int t = threadIdx.x;
    const int s0 = cbase[b], s1 = cbase[b + 1];
    if (t < CSZ) hist[t] = 0;
    __syncthreads();
    for (int i = s0 + t; i < s1; i += 256)
        atomicAdd(&hist[(cpairs[i].x >> 20) & (CSZ - 1)], 1);
    __syncthreads();
    if (t < CSZ) scn[t] = hist[t];
    __syncthreads();
    for (int off = 1; off < CSZ; off <<= 1) {
        int u = 0;
        if (t < CSZ && t >= off) u = scn[t - off];
        __syncthreads();
        if (t < CSZ) scn[t] += u;
        __syncthreads();
    }
    if (t < CSZ) {
        const int base = s0 + scn[t] - hist[t];   // exclusive
        const int node = (b << CBITS) + t;
        if (node < N) offs[node] = base;
        hist[t] = base;                            // becomes cursor
    }
    __syncthreads();
    for (int i = s0 + t; i < s1; i += 256) {
        const int2 p = cpairs[i];
        const int pos = atomicAdd(&hist[(p.x >> 20) & (CSZ - 1)], 1);
        pairs[pos] = make_int2(p.x & 0xFFFFF, p.y);
    }
}

// ---------------- gather-aggregate v3: one wave per node ----------------
// 32 lanes cover one row; sub = lane>>5 selects one of 2 parallel edges.
// fp16: 8B/lane loads; fp32: 16B/lane loads. Unroll 4 -> 8 edges in flight.
template <bool FP16X>
__global__ __launch_bounds__(256) void sage_gather(
    const void* __restrict__ xrows,
    const int2* __restrict__ pairs,
    const int* __restrict__ offs,
    void* __restrict__ agg,
    int N)
{
    int node = (blockIdx.x * blockDim.x + threadIdx.x) >> 6;
    const int lane = threadIdx.x & 63;
    if (node >= N) return;
    node = __builtin_amdgcn_readfirstlane(node);
    const int beg = offs[node];
    const int end = offs[node + 1];
    const int sub = lane >> 5;
    const int cl  = lane & 31;

    const __half* __restrict__ xh = (const __half*)xrows;
    const float*  __restrict__ xf = (const float*)xrows;

    float a0 = 0.f, a1 = 0.f, a2 = 0.f, a3 = 0.f;
    int k = beg;
    for (; k + 8 <= end; k += 8) {
        int s_[4]; float w_[4];
#pragma unroll
        for (int i = 0; i < 4; ++i) {
            const int2 ea = pairs[k + 2 * i + 0];   // uniform addr -> s_load
            const int2 eb = pairs[k + 2 * i + 1];
            s_[i] = sub ? eb.x : ea.x;
            w_[i] = __int_as_float(sub ? eb.y : ea.y);
        }
        if (FP16X) {
            float2 raw[4];
#pragma unroll
            for (int i = 0; i < 4; ++i)
                raw[i] = *reinterpret_cast<const float2*>(&xh[(size_t)s_[i] * D + cl * 4]);
#pragma unroll
            for (int i = 0; i < 4; ++i) {
                union { float2 f2; __half2 h[2]; } u;
                u.f2 = raw[i];
                const float2 f01 = __half22float2(u.h[0]);
                const float2 f23 = __half22float2(u.h[1]);
                a0 = fmaf(f01.x, w_[i], a0);
                a1 = fmaf(f01.y, w_[i], a1);
                a2 = fmaf(f23.x, w_[i], a2);
                a3 = fmaf(f23.y, w_[i], a3);
            }
        } else {
            float4 raw[4];
#pragma unroll
            for (int i = 0; i < 4; ++i)
                raw[i] = *reinterpret_cast<const float4*>(&xf[(size_t)s_[i] * D + cl * 4]);
#pragma unroll
            for (int i = 0; i < 4; ++i) {
                a0 = fmaf(raw[i].x, w_[i], a0);
                a1 = fmaf(raw[i].y, w_[i], a1);
                a2 = fmaf(raw[i].z, w_[i], a2);
                a3 = fmaf(raw[i].w, w_[i], a3);
            }
        }
    }
    // tail: alternate subs over remaining edges
    for (int t = 0; k + t < end; ++t) {
        if (sub == (t & 1)) {
            const int2 p = pairs[k + t];
            const float w = __int_as_float(p.y);
            if (FP16X) {
                union { float2 f2; __half2 h[2]; } u;
                u.f2 = *reinterpret_cast<const float2*>(&xh[(size_t)p.x * D + cl * 4]);
                const float2 f01 = __half22float2(u.h[0]);
                const float2 f23 = __half22float2(u.h[1]);
                a0 = fmaf(f01.x, w, a0); a1 = fmaf(f01.y, w, a1);
                a2 = fmaf(f23.x, w, a2); a3 = fmaf(f23.y, w, a3);
            } else {
                const float4 v = *reinterpret_cast<const float4*>(&xf[(size_t)p.x * D + cl * 4]);
                a0 = fmaf(v.x, w, a0); a1 = fmaf(v.y, w, a1);
                a2 = fmaf(v.z, w, a2); a3 = fmaf(v.w, w, a3);
            }
        }
    }
    // combine the two sub-halves (lane l <-> l+32, same cl)
    a0 += __shfl_xor(a0, 32, 64);
    a1 += __shfl_xor(a1, 32, 64);
    a2 += __shfl_xor(a2, 32, 64);
    a3 += __shfl_xor(a3, 32, 64);

    if (sub == 0) {
        if (FP16X) {
            union { __half2 h[2]; int2 i2; } u;
            u.h[0] = __floats2half2_rn(a0, a1);
            u.h[1] = __floats2half2_rn(a2, a3);
            *reinterpret_cast<int2*>(&((__half*)agg)[(size_t)node * D + cl * 4]) = u.i2;
        } else {
            *reinterpret_cast<float4*>(&((float*)agg)[(size_t)node * D + cl * 4]) =
                make_float4(a0, a1, a2, a3);
        }
    }
}

// ---------------- fallback atomic scatter (ws too small) ----------------
__global__ __launch_bounds__(256) void sage_scatter(
    const float* __restrict__ x,
    const int* __restrict__ esrc,
    const int* __restrict__ edst,
    const float* __restrict__ ew,
    float* agg, int E)
{
    const int lane = threadIdx.x & 63;
    const int warp = (blockIdx.x * blockDim.x + threadIdx.x) >> 6;
    const int nwarps = (gridDim.x * blockDim.x) >> 6;
    const float2* __restrict__ x2 = reinterpret_cast<const float2*>(x);
    for (int e = warp; e < E; e += nwarps) {
        const int s = esrc[e];
        const int d = edst[e];
        const float w = ew[e];
        const float2 xv = x2[s * 64 + lane];
        atomicAdd(&agg[d * D + lane * 2 + 0], xv.x * w);
        atomicAdd(&agg[d * D + lane * 2 + 1], xv.y * w);
    }
}

// ------------- MFMA fused linear(l)+linear(r)+bias+L1-normalize -------------
__global__ __launch_bounds__(256) void sage_linear_norm_mfma(
    const __half* __restrict__ aggh,   // [N][128]
    const __half* __restrict__ xh,     // [N][128]
    const __half* __restrict__ wt,     // [128 cols][256 k]
    const float* __restrict__ bl,
    const float* __restrict__ br,
    float* __restrict__ out,
    int N)
{
    __shared__ __half a_s[64][136];
    __shared__ __half w_s[128][136];
    const int tid = threadIdx.x;
    const int bn = blockIdx.x * 64;
    const int wv = tid >> 6;     // wave -> row group
    const int l  = tid & 63;
    const int lr = l & 15;       // fragment row/col
    const int lq = l >> 4;       // quarter -> k-subrange / C row group

    f32x4 acc[8];
#pragma unroll
    for (int t = 0; t < 8; ++t) acc[t] = f32x4{0.f, 0.f, 0.f, 0.f};

    const int ar  = tid >> 2;          // A staging: row 0..63
    const int as  = (tid & 3) * 32;    // A staging: 64B offset
    const int wr  = tid >> 1;          // W staging: col-row 0..127
    const int wsg = (tid & 1) * 64;    // W staging: 128B offset

#pragma unroll
    for (int c = 0; c < 2; ++c) {
        const __half* __restrict__ A = c ? xh : aggh;
        __syncthreads();   // previous chunk consumed
        {
            const int gn = bn + ar;
            half8 v0 = {}, v1 = {}, v2 = {}, v3 = {};
            if (gn < N) {
                const half8* src = reinterpret_cast<const half8*>(&A[(size_t)gn * D + as]);
                v0 = src[0]; v1 = src[1]; v2 = src[2]; v3 = src[3];
            }
            half8* dst = reinterpret_cast<half8*>(&a_s[ar][as]);
            dst[0] = v0; dst[1] = v1; dst[2] = v2; dst[3] = v3;
        }
        {
            const half8* src = reinterpret_cast<const half8*>(&wt[(size_t)wr * 256 + c * 128 + wsg]);
            half8* dst = reinterpret_cast<half8*>(&w_s[wr][wsg]);
#pragma unroll
            for (int j = 0; j < 8; ++j) dst[j] = src[j];
        }
        __syncthreads();

#pragma unroll
        for (int ks = 0; ks < 4; ++ks) {
            const int k0 = ks * 32 + lq * 8;
            const half8 af = *reinterpret_cast<const half8*>(&a_s[wv * 16 + lr][k0]);
#pragma unroll
            for (int t = 0; t < 8; ++t) {
                const half8 bf = *reinterpret_cast<const half8*>(&w_s[t * 16 + lr][k0]);
                acc[t] = __builtin_amdgcn_mfma_f32_16x16x32_f16(af, bf, acc[t], 0, 0, 0);
            }
        }
    }

    float bias[8];
#pragma unroll
    for (int t = 0; t < 8; ++t) {
        const int cidx = t * 16 + lr;
        bias[t] = bl[cidx] + br[cidx];
    }
    float v[8][4];
    float s0 = 0.f, s1 = 0.f, s2 = 0.f, s3 = 0.f;
#pragma unroll
    for (int t = 0; t < 8; ++t) {
        v[t][0] = acc[t][0] + bias[t];
        v[t][1] = acc[t][1] + bias[t];
        v[t][2] = acc[t][2] + bias[t];
        v[t][3] = acc[t][3] + bias[t];
        s0 += fabsf(v[t][0]); s1 += fabsf(v[t][1]);
        s2 += fabsf(v[t][2]); s3 += fabsf(v[t][3]);
    }
#pragma unroll
    for (int m = 1; m < 16; m <<= 1) {
        s0 += __shfl_xor(s0, m, 64);
        s1 += __shfl_xor(s1, m, 64);
        s2 += __shfl_xor(s2, m, 64);
        s3 += __shfl_xor(s3, m, 64);
    }
    const float r0 = 1.0f / fmaxf(s0, 1e-12f);
    const float r1 = 1.0f / fmaxf(s1, 1e-12f);
    const float r2 = 1.0f / fmaxf(s2, 1e-12f);
    const float r3 = 1.0f / fmaxf(s3, 1e-12f);

    const int nd0 = bn + wv * 16 + lq * 4;
#pragma unroll
    for (int r = 0; r < 4; ++r) {
        const int nd = nd0 + r;
        if (nd < N) {
            const float ri = (r == 0) ? r0 : (r == 1) ? r1 : (r == 2) ? r2 : r3;
#pragma unroll
            for (int t = 0; t < 8; ++t)
                out[(size_t)nd * D + t * 16 + lr] = v[t][r] * ri;
        }
    }
}

// ------------- fp32 fallback linear (tier B/C) -------------
__global__ __launch_bounds__(256) void sage_linear_norm(
    const float* agg, const float* __restrict__ x,
    const float* __restrict__ Wl, const float* __restrict__ bl,
    const float* __restrict__ Wr, const float* __restrict__ br,
    float* out, int N)
{
    __shared__ float a_s[64][68];
    __shared__ float w_s[64][132];
    const int tid = threadIdx.x;
    const int jg = tid & 31;
    const int ng = tid >> 5;
    const int bn = blockIdx.x * 64;

    float acc[8][4];
#pragma unroll
    for (int i = 0; i < 8; ++i) {
        acc[i][0] = 0.f; acc[i][1] = 0.f; acc[i][2] = 0.f; acc[i][3] = 0.f;
    }
    const int sn  = tid >> 2;
    const int skb = (tid & 3) << 4;
    const int wr  = tid >> 5;
    const int wc  = (tid & 31) << 2;

    for (int c = 0; c < 4; ++c) {
        const float* A = (c < 2) ? agg : x;
        const float* __restrict__ W = (c < 2) ? Wl : Wr;
        const int kb = (c & 1) << 6;
        __syncthreads();
        const int gn = bn + sn;
#pragma unroll
        for (int it = 0; it < 4; ++it) {
            float4 vv = make_float4(0.f, 0.f, 0.f, 0.f);
            if (gn < N)
                vv = *reinterpret_cast<const float4*>(&A[(size_t)gn * D + kb + skb + it * 4]);
            *reinterpret_cast<float4*>(&a_s[sn][skb + it * 4]) = vv;
        }
#pragma unroll
        for (int it = 0; it < 8; ++it) {
            const int row = it * 8 + wr;
            const float4 vv = *reinterpret_cast<const float4*>(&W[(size_t)(kb + row) * D + wc]);
            *reinterpret_cast<float4*>(&w_s[row][wc]) = vv;
        }
        __syncthreads();
#pragma unroll 4
        for (int kk = 0; kk < 64; kk += 4) {
            const float4 w0 = *reinterpret_cast<const float4*>(&w_s[kk + 0][jg << 2]);
            const float4 w1 = *reinterpret_cast<const float4*>(&w_s[kk + 1][jg << 2]);
            const float4 w2 = *reinterpret_cast<const float4*>(&w_s[kk + 2][jg << 2]);
            const float4 w3 = *reinterpret_cast<const float4*>(&w_s[kk + 3][jg << 2]);
#pragma unroll
            for (int i = 0; i < 8; ++i) {
                const float4 av = *reinterpret_cast<const float4*>(&a_s[(ng << 3) + i][kk]);
                acc[i][0] = fmaf(av.w, w3.x, fmaf(av.z, w2.x, fmaf(av.y, w1.x, fmaf(av.x, w0.x, acc[i][0]))));
                acc[i][1] = fmaf(av.w, w3.y, fmaf(av.z, w2.y, fmaf(av.y, w1.y, fmaf(av.x, w0.y, acc[i][1]))));
                acc[i][2] = fmaf(av.w, w3.z, fmaf(av.z, w2.z, fmaf(av.y, w1.z, fmaf(av.x, w0.z, acc[i][2]))));
                acc[i][3] = fmaf(av.w, w3.w, fmaf(av.z, w2.w, fmaf(av.y, w1.w, fmaf(av.x, w0.w, acc[i][3]))));
            }
        }
    }
    const float4 bl4 = *reinterpret_cast<const float4*>(&bl[jg << 2]);
    const float4 br4 = *reinterpret_cast<const float4*>(&br[jg << 2]);
    const float bx = bl4.x + br4.x, by = bl4.y + br4.y,
                bz = bl4.z + br4.z, bw = bl4.w + br4.w;
#pragma unroll
    for (int i = 0; i < 8; ++i) {
        const float v0 = acc[i][0] + bx;
        const float v1 = acc[i][1] + by;
        const float v2 = acc[i][2] + bz;
        const float v3 = acc[i][3] + bw;
        float s = fabsf(v0) + fabsf(v1) + fabsf(v2) + fabsf(v3);
#pragma unroll
        for (int m = 1; m < 32; m <<= 1) s += __shfl_xor(s, m, 64);
        s = fmaxf(s, 1e-12f);
        const float r = 1.0f / s;
        const int n = bn + (ng << 3) + i;
        if (n < N) {
            const float4 o = make_float4(v0 * r, v1 * r, v2 * r, v3 * r);
            *reinterpret_cast<float4*>(&out[(size_t)n * D + (jg << 2)]) = o;
        }
    }
}

extern "C" void kernel_launch(void* const* d_in, const int* in_sizes, int n_in,
                              void* d_out, int out_size, void* d_ws, size_t ws_size,
                              hipStream_t stream) {
    const float* x    = (const float*)d_in[0];
    const int*   esrc = (const int*)  d_in[1];
    const int*   edst = (const int*)  d_in[2];
    const float* ew   = (const float*)d_in[3];
    const float* Wl   = (const float*)d_in[4];
    const float* bl   = (const float*)d_in[5];
    const float* Wr   = (const float*)d_in[6];
    const float* br   = (const float*)d_in[7];
    float* out = (float*)d_out;

    const int N = in_sizes[0] / D;
    const int E = in_sizes[1];

    // ws: bhist[NPART*NB] | cbase[NB+1] | offs[N+1] | cpairs[E] | pairs[E] | xh | aggh | wt
    auto align256 = [](size_t v) { return (v + 255) & ~size_t(255); };
    size_t off_bhist  = 0;
    size_t off_cbase  = align256(off_bhist  + (size_t)NPART * NB * 4);
    size_t off_offs   = align256(off_cbase  + (size_t)(NB + 1) * 4);
    size_t off_cpairs = align256(off_offs   + (size_t)(N + 1) * 4);
    size_t off_pairs  = align256(off_cpairs + (size_t)E * 8);
    size_t off_xh     = align256(off_pairs  + (size_t)E * 8);
    size_t off_aggh   = align256(off_xh     + (size_t)N * D * 2);
    size_t off_wt     = align256(off_aggh   + (size_t)N * D * 2);
    size_t need_b     = off_xh;                        // sorted fp32 path
    size_t need_a     = off_wt + (size_t)256 * D * 2;  // full fp16 MFMA path

    const bool fits_meta = (N <= (1 << 20)) && ((N + CSZ - 1) >> CBITS) <= NB;

    if (ws_size >= need_b && fits_meta) {
        char* ws = (char*)d_ws;
        int*  bhist  = (int*) (ws + off_bhist);
        int*  cbase  = (int*) (ws + off_cbase);
        int*  offs   = (int*) (ws + off_offs);
        int2* cpairs = (int2*)(ws + off_cpairs);
        int2* pairs  = (int2*)(ws + off_pairs);
        __half2* xh  = (__half2*)(ws + off_xh);
        __half*  agh = (__half*)(ws + off_aggh);
        __half*  wt  = (__half*)(ws + off_wt);

        const bool mfma = (ws_size >= need_a);
        const int chunk = (E + NPART - 1) / NPART;
        const int nbu = (N + CSZ - 1) >> CBITS;

        if (mfma) {
            cvt_x_fp16<<<4096, 256, 0, stream>>>((const float4*)x, xh, N * (D / 4));
            wt_build<<<128, 256, 0, stream>>>(Wl, Wr, wt);
        }
        coarse_count<<<NPART, 256, 0, stream>>>(edst, bhist, E, chunk);
        coarse_scan2<<<1, NB, 0, stream>>>(bhist, cbase, offs, N, E, NPART);
        coarse_partition<<<NPART, 256, 0, stream>>>(esrc, edst, ew, bhist, cpairs, E, chunk);
        fine_sort<<<nbu, 256, 0, stream>>>(cpairs, cbase, offs, pairs, N);

        const int gb = (N * 64 + 255) / 256;   // one wave per node
        const int nb = (N + 63) / 64;
        if (mfma) {
            sage_gather<true ><<<gb, 256, 0, stream>>>(xh, pairs, offs, agh, N);
            sage_linear_norm_mfma<<<nb, 256, 0, stream>>>(agh, (const __half*)xh, wt,
                                                          bl, br, out, N);
        } else {
            sage_gather<false><<<gb, 256, 0, stream>>>(x, pairs, offs, out, N);
            sage_linear_norm<<<nb, 256, 0, stream>>>(out, x, Wl, bl, Wr, br, out, N);
        }
    } else {
        hipMemsetAsync(out, 0, (size_t)N * D * sizeof(float), stream);
        sage_scatter<<<2048, 256, 0, stream>>>(x, esrc, edst, ew, out, E);
        const int nb = (N + 63) / 64;
        sage_linear_norm<<<nb, 256, 0, stream>>>(out, x, Wl, bl, Wr, br, out, N);
    }
}

// Round 8
// 161.020 us; speedup vs baseline: 1.4581x; 1.4581x over previous
//
#include <hip/hip_runtime.h>
#include <hip/hip_fp16.h>

// SAGEConv: agg = segment_sum(x[src]*w, dst); out = agg@W_l + b_l + x@W_r + b_r;
// out /= max(sum|out|, 1e-12) row-wise.  N=100000, E=1600000, D=128.
//
// R8: fix R7's 88us serial coarse_scan2 (1 block, 256 dependent RMW iters).
// Replaced by: bucket_scan (16 blocks x 64 thr, one bucket/thread, batched
// 8-wide loads -> pipelined latency) + the old trivial 1024-wide coarse_scan.
// coarse_partition folds cbase[t] into its cursor init. Gather v3 and MFMA
// linear unchanged.

static constexpr int D = 128;
static constexpr int NB = 1024;     // coarse buckets
static constexpr int CBITS = 7;     // nodes per bucket = 128
static constexpr int CSZ = 1 << CBITS;
static constexpr int NPART = 256;   // partition blocks

typedef _Float16 half8 __attribute__((ext_vector_type(8)));
typedef float f32x4 __attribute__((ext_vector_type(4)));

// ---------------- x -> fp16 staging ----------------
__global__ __launch_bounds__(256) void cvt_x_fp16(
    const float4* __restrict__ x4, __half2* __restrict__ xh2, int n4)
{
    int i = blockIdx.x * blockDim.x + threadIdx.x;
    int stride = gridDim.x * blockDim.x;
    for (; i < n4; i += stride) {
        float4 v = x4[i];
        xh2[2 * i + 0] = __floats2half2_rn(v.x, v.y);
        xh2[2 * i + 1] = __floats2half2_rn(v.z, v.w);
    }
}

// ---------------- W pre-transpose: WT[c][k] fp16, k<128 -> Wl, else Wr ----
__global__ __launch_bounds__(256) void wt_build(
    const float* __restrict__ Wl, const float* __restrict__ Wr,
    __half* __restrict__ wt)
{
    const int idx = blockIdx.x * blockDim.x + threadIdx.x;  // 128 blocks x 256
    if (idx >= 128 * 256) return;
    const int c = idx >> 8;
    const int k = idx & 255;
    const float v = (k < 128) ? Wl[(size_t)k * D + c] : Wr[(size_t)(k - 128) * D + c];
    wt[(size_t)c * 256 + k] = __float2half(v);
}

// ---------------- two-level counting sort (deterministic bases) ----------
__global__ __launch_bounds__(256) void coarse_count(
    const int* __restrict__ edst, int* __restrict__ bhist, int E, int chunk)
{
    __shared__ int hist[NB];
    for (int t = threadIdx.x; t < NB; t += 256) hist[t] = 0;
    __syncthreads();
    const int beg = blockIdx.x * chunk;
    const int end = min(E, beg + chunk);
    for (int e = beg + threadIdx.x; e < end; e += 256)
        atomicAdd(&hist[edst[e] >> CBITS], 1);
    __syncthreads();
    for (int t = threadIdx.x; t < NB; t += 256)
        bhist[(size_t)blockIdx.x * NB + t] = hist[t];
}

// grid 16 x 64: one bucket per thread. Scan its NPART per-block counts into
// relative bases (batched 8-wide loads -> latency pipelines); totals to ctot.
__global__ __launch_bounds__(64) void bucket_scan(
    int* __restrict__ bhist, int* __restrict__ ctot)
{
    const int t = blockIdx.x * 64 + threadIdx.x;   // bucket 0..NB-1
    int run = 0;
    for (int b = 0; b < NPART; b += 8) {
        int v[8];
#pragma unroll
        for (int i = 0; i < 8; ++i)
            v[i] = bhist[(size_t)(b + i) * NB + t];
#pragma unroll
        for (int i = 0; i < 8; ++i) {
            const int c = v[i];
            bhist[(size_t)(b + i) * NB + t] = run;   // relative base
            run += c;
        }
    }
    ctot[t] = run;
}

// 1 block x NB: exclusive scan of bucket totals -> cbase; offs[N]=E.
__global__ __launch_bounds__(NB) void coarse_scan(
    const int* __restrict__ ctot, int* __restrict__ cbase,
    int* __restrict__ offs, int N, int E)
{
    __shared__ int s[NB];
    const int t = threadIdx.x;
    const int v = ctot[t];
    s[t] = v;
    __syncthreads();
    for (int off = 1; off < NB; off <<= 1) {
        const int u = (t >= off) ? s[t - off] : 0;
        __syncthreads();
        s[t] += u;
        __syncthreads();
    }
    cbase[t] = s[t] - v;
    if (t == NB - 1) { cbase[NB] = s[t]; offs[N] = E; }
}

// partition edges into coarse buckets; pair = (dst_low7<<20 | src, w_bits)
__global__ __launch_bounds__(256) void coarse_partition(
    const int* __restrict__ esrc, const int* __restrict__ edst,
    const float* __restrict__ ew, const int* __restrict__ bhist,
    const int* __restrict__ cbase,
    int2* __restrict__ cpairs, int E, int chunk)
{
    __shared__ int cur[NB];
    for (int t = threadIdx.x; t < NB; t += 256)
        cur[t] = bhist[(size_t)blockIdx.x * NB + t] + cbase[t];  // absolute
    __syncthreads();
    const int beg = blockIdx.x * chunk;
    const int end = min(E, beg + chunk);
    for (int e = beg + threadIdx.x; e < end; e += 256) {
        const int d = edst[e];
        const int pos = atomicAdd(&cur[d >> CBITS], 1);
        cpairs[pos] = make_int2(((d & (CSZ - 1)) << 20) | esrc[e],
                                __float_as_int(ew[e]));
    }
}

// one block per coarse bucket: fine 128-bin counting sort + offs[] write
__global__ __launch_bounds__(256) void fine_sort(
    const int2* __restrict__ cpairs, const int* __restrict__ cbase,
    int* __restrict__ offs, int2* __restrict__ pairs, int N)
{
    __shared__ int hist[CSZ];
    __shared__ int scn[CSZ];
    const int b = blockIdx.x;
    const int t = threadIdx.x;
    const int s0 = cbase[b], s1 = cbase[b + 1];
    if (t < CSZ) hist[t] = 0;
    __syncthreads();
    for (int i = s0 + t; i < s1; i += 256)
        atomicAdd(&hist[(cpairs[i].x >> 20) & (CSZ - 1)], 1);
    __syncthreads();
    if (t < CSZ) scn[t] = hist[t];
    __syncthreads();
    for (int off = 1; off < CSZ; off <<= 1) {
        int u = 0;
        if (t < CSZ && t >= off) u = scn[t - off];
        __syncthreads();
        if (t < CSZ) scn[t] += u;
        __syncthreads();
    }
    if (t < CSZ) {
        const int base = s0 + scn[t] - hist[t];   // exclusive
        const int node = (b << CBITS) + t;
        if (node < N) offs[node] = base;
        hist[t] = base;                            // becomes cursor
    }
    __syncthreads();
    for (int i = s0 + t; i < s1; i += 256) {
        const int2 p = cpairs[i];
        const int pos = atomicAdd(&hist[(p.x >> 20) & (CSZ - 1)], 1);
        pairs[pos] = make_int2(p.x & 0xFFFFF, p.y);
    }
}

// ---------------- gather-aggregate v3: one wave per node ----------------
// 32 lanes cover one row; sub = lane>>5 selects one of 2 parallel edges.
// fp16: 8B/lane loads; fp32: 16B/lane loads. Unroll 4 -> 8 edges in flight.
template <bool FP16X>
__global__ __launch_bounds__(256) void sage_gather(
    const void* __restrict__ xrows,
    const int2* __restrict__ pairs,
    const int* __restrict__ offs,
    void* __restrict__ agg,
    int N)
{
    int node = (blockIdx.x * blockDim.x + threadIdx.x) >> 6;
    const int lane = threadIdx.x & 63;
    if (node >= N) return;
    node = __builtin_amdgcn_readfirstlane(node);
    const int beg = offs[node];
    const int end = offs[node + 1];
    const int sub = lane >> 5;
    const int cl  = lane & 31;

    const __half* __restrict__ xh = (const __half*)xrows;
    const float*  __restrict__ xf = (const float*)xrows;

    float a0 = 0.f, a1 = 0.f, a2 = 0.f, a3 = 0.f;
    int k = beg;
    for (; k + 8 <= end; k += 8) {
        int s_[4]; float w_[4];
#pragma unroll
        for (int i = 0; i < 4; ++i) {
            const int2 ea = pairs[k + 2 * i + 0];   // uniform addr -> s_load
            const int2 eb = pairs[k + 2 * i + 1];
            s_[i] = sub ? eb.x : ea.x;
            w_[i] = __int_as_float(sub ? eb.y : ea.y);
        }
        if (FP16X) {
            float2 raw[4];
#pragma unroll
            for (int i = 0; i < 4; ++i)
                raw[i] = *reinterpret_cast<const float2*>(&xh[(size_t)s_[i] * D + cl * 4]);
#pragma unroll
            for (int i = 0; i < 4; ++i) {
                union { float2 f2; __half2 h[2]; } u;
                u.f2 = raw[i];
                const float2 f01 = __half22float2(u.h[0]);
                const float2 f23 = __half22float2(u.h[1]);
                a0 = fmaf(f01.x, w_[i], a0);
                a1 = fmaf(f01.y, w_[i], a1);
                a2 = fmaf(f23.x, w_[i], a2);
                a3 = fmaf(f23.y, w_[i], a3);
            }
        } else {
            float4 raw[4];
#pragma unroll
            for (int i = 0; i < 4; ++i)
                raw[i] = *reinterpret_cast<const float4*>(&xf[(size_t)s_[i] * D + cl * 4]);
#pragma unroll
            for (int i = 0; i < 4; ++i) {
                a0 = fmaf(raw[i].x, w_[i], a0);
                a1 = fmaf(raw[i].y, w_[i], a1);
                a2 = fmaf(raw[i].z, w_[i], a2);
                a3 = fmaf(raw[i].w, w_[i], a3);
            }
        }
    }
    // tail: alternate subs over remaining edges
    for (int t = 0; k + t < end; ++t) {
        if (sub == (t & 1)) {
            const int2 p = pairs[k + t];
            const float w = __int_as_float(p.y);
            if (FP16X) {
                union { float2 f2; __half2 h[2]; } u;
                u.f2 = *reinterpret_cast<const float2*>(&xh[(size_t)p.x * D + cl * 4]);
                const float2 f01 = __half22float2(u.h[0]);
                const float2 f23 = __half22float2(u.h[1]);
                a0 = fmaf(f01.x, w, a0); a1 = fmaf(f01.y, w, a1);
                a2 = fmaf(f23.x, w, a2); a3 = fmaf(f23.y, w, a3);
            } else {
                const float4 v = *reinterpret_cast<const float4*>(&xf[(size_t)p.x * D + cl * 4]);
                a0 = fmaf(v.x, w, a0); a1 = fmaf(v.y, w, a1);
                a2 = fmaf(v.z, w, a2); a3 = fmaf(v.w, w, a3);
            }
        }
    }
    // combine the two sub-halves (lane l <-> l+32, same cl)
    a0 += __shfl_xor(a0, 32, 64);
    a1 += __shfl_xor(a1, 32, 64);
    a2 += __shfl_xor(a2, 32, 64);
    a3 += __shfl_xor(a3, 32, 64);

    if (sub == 0) {
        if (FP16X) {
            union { __half2 h[2]; int2 i2; } u;
            u.h[0] = __floats2half2_rn(a0, a1);
            u.h[1] = __floats2half2_rn(a2, a3);
            *reinterpret_cast<int2*>(&((__half*)agg)[(size_t)node * D + cl * 4]) = u.i2;
        } else {
            *reinterpret_cast<float4*>(&((float*)agg)[(size_t)node * D + cl * 4]) =
                make_float4(a0, a1, a2, a3);
        }
    }
}

// ---------------- fallback atomic scatter (ws too small) ----------------
__global__ __launch_bounds__(256) void sage_scatter(
    const float* __restrict__ x,
    const int* __restrict__ esrc,
    const int* __restrict__ edst,
    const float* __restrict__ ew,
    float* agg, int E)
{
    const int lane = threadIdx.x & 63;
    const int warp = (blockIdx.x * blockDim.x + threadIdx.x) >> 6;
    const int nwarps = (gridDim.x * blockDim.x) >> 6;
    const float2* __restrict__ x2 = reinterpret_cast<const float2*>(x);
    for (int e = warp; e < E; e += nwarps) {
        const int s = esrc[e];
        const int d = edst[e];
        const float w = ew[e];
        const float2 xv = x2[s * 64 + lane];
        atomicAdd(&agg[d * D + lane * 2 + 0], xv.x * w);
        atomicAdd(&agg[d * D + lane * 2 + 1], xv.y * w);
    }
}

// ------------- MFMA fused linear(l)+linear(r)+bias+L1-normalize -------------
__global__ __launch_bounds__(256) void sage_linear_norm_mfma(
    const __half* __restrict__ aggh,   // [N][128]
    const __half* __restrict__ xh,     // [N][128]
    const __half* __restrict__ wt,     // [128 cols][256 k]
    const float* __restrict__ bl,
    const float* __restrict__ br,
    float* __restrict__ out,
    int N)
{
    __shared__ __half a_s[64][136];
    __shared__ __half w_s[128][136];
    const int tid = threadIdx.x;
    const int bn = blockIdx.x * 64;
    const int wv = tid >> 6;     // wave -> row group
    const int l  = tid & 63;
    const int lr = l & 15;       // fragment row/col
    const int lq = l >> 4;       // quarter -> k-subrange / C row group

    f32x4 acc[8];
#pragma unroll
    for (int t = 0; t < 8; ++t) acc[t] = f32x4{0.f, 0.f, 0.f, 0.f};

    const int ar  = tid >> 2;          // A staging: row 0..63
    const int as  = (tid & 3) * 32;    // A staging: 64B offset
    const int wr  = tid >> 1;          // W staging: col-row 0..127
    const int wsg = (tid & 1) * 64;    // W staging: 128B offset

#pragma unroll
    for (int c = 0; c < 2; ++c) {
        const __half* __restrict__ A = c ? xh : aggh;
        __syncthreads();   // previous chunk consumed
        {
            const int gn = bn + ar;
            half8 v0 = {}, v1 = {}, v2 = {}, v3 = {};
            if (gn < N) {
                const half8* src = reinterpret_cast<const half8*>(&A[(size_t)gn * D + as]);
                v0 = src[0]; v1 = src[1]; v2 = src[2]; v3 = src[3];
            }
            half8* dst = reinterpret_cast<half8*>(&a_s[ar][as]);
            dst[0] = v0; dst[1] = v1; dst[2] = v2; dst[3] = v3;
        }
        {
            const half8* src = reinterpret_cast<const half8*>(&wt[(size_t)wr * 256 + c * 128 + wsg]);
            half8* dst = reinterpret_cast<half8*>(&w_s[wr][wsg]);
#pragma unroll
            for (int j = 0; j < 8; ++j) dst[j] = src[j];
        }
        __syncthreads();

#pragma unroll
        for (int ks = 0; ks < 4; ++ks) {
            const int k0 = ks * 32 + lq * 8;
            const half8 af = *reinterpret_cast<const half8*>(&a_s[wv * 16 + lr][k0]);
#pragma unroll
            for (int t = 0; t < 8; ++t) {
                const half8 bf = *reinterpret_cast<const half8*>(&w_s[t * 16 + lr][k0]);
                acc[t] = __builtin_amdgcn_mfma_f32_16x16x32_f16(af, bf, acc[t], 0, 0, 0);
            }
        }
    }

    float bias[8];
#pragma unroll
    for (int t = 0; t < 8; ++t) {
        const int cidx = t * 16 + lr;
        bias[t] = bl[cidx] + br[cidx];
    }
    float v[8][4];
    float s0 = 0.f, s1 = 0.f, s2 = 0.f, s3 = 0.f;
#pragma unroll
    for (int t = 0; t < 8; ++t) {
        v[t][0] = acc[t][0] + bias[t];
        v[t][1] = acc[t][1] + bias[t];
        v[t][2] = acc[t][2] + bias[t];
        v[t][3] = acc[t][3] + bias[t];
        s0 += fabsf(v[t][0]); s1 += fabsf(v[t][1]);
        s2 += fabsf(v[t][2]); s3 += fabsf(v[t][3]);
    }
#pragma unroll
    for (int m = 1; m < 16; m <<= 1) {
        s0 += __shfl_xor(s0, m, 64);
        s1 += __shfl_xor(s1, m, 64);
        s2 += __shfl_xor(s2, m, 64);
        s3 += __shfl_xor(s3, m, 64);
    }
    const float r0 = 1.0f / fmaxf(s0, 1e-12f);
    const float r1 = 1.0f / fmaxf(s1, 1e-12f);
    const float r2 = 1.0f / fmaxf(s2, 1e-12f);
    const float r3 = 1.0f / fmaxf(s3, 1e-12f);

    const int nd0 = bn + wv * 16 + lq * 4;
#pragma unroll
    for (int r = 0; r < 4; ++r) {
        const int nd = nd0 + r;
        if (nd < N) {
            const float ri = (r == 0) ? r0 : (r == 1) ? r1 : (r == 2) ? r2 : r3;
#pragma unroll
            for (int t = 0; t < 8; ++t)
                out[(size_t)nd * D + t * 16 + lr] = v[t][r] * ri;
        }
    }
}

// ------------- fp32 fallback linear (tier B/C) -------------
__global__ __launch_bounds__(256) void sage_linear_norm(
    const float* agg, const float* __restrict__ x,
    const float* __restrict__ Wl, const float* __restrict__ bl,
    const float* __restrict__ Wr, const float* __restrict__ br,
    float* out, int N)
{
    __shared__ float a_s[64][68];
    __shared__ float w_s[64][132];
    const int tid = threadIdx.x;
    const int jg = tid & 31;
    const int ng = tid >> 5;
    const int bn = blockIdx.x * 64;

    float acc[8][4];
#pragma unroll
    for (int i = 0; i < 8; ++i) {
        acc[i][0] = 0.f; acc[i][1] = 0.f; acc[i][2] = 0.f; acc[i][3] = 0.f;
    }
    const int sn  = tid >> 2;
    const int skb = (tid & 3) << 4;
    const int wr  = tid >> 5;
    const int wc  = (tid & 31) << 2;

    for (int c = 0; c < 4; ++c) {
        const float* A = (c < 2) ? agg : x;
        const float* __restrict__ W = (c < 2) ? Wl : Wr;
        const int kb = (c & 1) << 6;
        __syncthreads();
        const int gn = bn + sn;
#pragma unroll
        for (int it = 0; it < 4; ++it) {
            float4 vv = make_float4(0.f, 0.f, 0.f, 0.f);
            if (gn < N)
                vv = *reinterpret_cast<const float4*>(&A[(size_t)gn * D + kb + skb + it * 4]);
            *reinterpret_cast<float4*>(&a_s[sn][skb + it * 4]) = vv;
        }
#pragma unroll
        for (int it = 0; it < 8; ++it) {
            const int row = it * 8 + wr;
            const float4 vv = *reinterpret_cast<const float4*>(&W[(size_t)(kb + row) * D + wc]);
            *reinterpret_cast<float4*>(&w_s[row][wc]) = vv;
        }
        __syncthreads();
#pragma unroll 4
        for (int kk = 0; kk < 64; kk += 4) {
            const float4 w0 = *reinterpret_cast<const float4*>(&w_s[kk + 0][jg << 2]);
            const float4 w1 = *reinterpret_cast<const float4*>(&w_s[kk + 1][jg << 2]);
            const float4 w2 = *reinterpret_cast<const float4*>(&w_s[kk + 2][jg << 2]);
            const float4 w3 = *reinterpret_cast<const float4*>(&w_s[kk + 3][jg << 2]);
#pragma unroll
            for (int i = 0; i < 8; ++i) {
                const float4 av = *reinterpret_cast<const float4*>(&a_s[(ng << 3) + i][kk]);
                acc[i][0] = fmaf(av.w, w3.x, fmaf(av.z, w2.x, fmaf(av.y, w1.x, fmaf(av.x, w0.x, acc[i][0]))));
                acc[i][1] = fmaf(av.w, w3.y, fmaf(av.z, w2.y, fmaf(av.y, w1.y, fmaf(av.x, w0.y, acc[i][1]))));
                acc[i][2] = fmaf(av.w, w3.z, fmaf(av.z, w2.z, fmaf(av.y, w1.z, fmaf(av.x, w0.z, acc[i][2]))));
                acc[i][3] = fmaf(av.w, w3.w, fmaf(av.z, w2.w, fmaf(av.y, w1.w, fmaf(av.x, w0.w, acc[i][3]))));
            }
        }
    }
    const float4 bl4 = *reinterpret_cast<const float4*>(&bl[jg << 2]);
    const float4 br4 = *reinterpret_cast<const float4*>(&br[jg << 2]);
    const float bx = bl4.x + br4.x, by = bl4.y + br4.y,
                bz = bl4.z + br4.z, bw = bl4.w + br4.w;
#pragma unroll
    for (int i = 0; i < 8; ++i) {
        const float v0 = acc[i][0] + bx;
        const float v1 = acc[i][1] + by;
        const float v2 = acc[i][2] + bz;
        const float v3 = acc[i][3] + bw;
        float s = fabsf(v0) + fabsf(v1) + fabsf(v2) + fabsf(v3);
#pragma unroll
        for (int m = 1; m < 32; m <<= 1) s += __shfl_xor(s, m, 64);
        s = fmaxf(s, 1e-12f);
        const float r = 1.0f / s;
        const int n = bn + (ng << 3) + i;
        if (n < N) {
            const float4 o = make_float4(v0 * r, v1 * r, v2 * r, v3 * r);
            *reinterpret_cast<float4*>(&out[(size_t)n * D + (jg << 2)]) = o;
        }
    }
}

extern "C" void kernel_launch(void* const* d_in, const int* in_sizes, int n_in,
                              void* d_out, int out_size, void* d_ws, size_t ws_size,
                              hipStream_t stream) {
    const float* x    = (const float*)d_in[0];
    const int*   esrc = (const int*)  d_in[1];
    const int*   edst = (const int*)  d_in[2];
    const float* ew   = (const float*)d_in[3];
    const float* Wl   = (const float*)d_in[4];
    const float* bl   = (const float*)d_in[5];
    const float* Wr   = (const float*)d_in[6];
    const float* br   = (const float*)d_in[7];
    float* out = (float*)d_out;

    const int N = in_sizes[0] / D;
    const int E = in_sizes[1];

    // ws: bhist[NPART*NB] | ctot[NB] | cbase[NB+1] | offs[N+1] | cpairs[E] |
    //     pairs[E] | xh | aggh | wt
    auto align256 = [](size_t v) { return (v + 255) & ~size_t(255); };
    size_t off_bhist  = 0;
    size_t off_ctot   = align256(off_bhist  + (size_t)NPART * NB * 4);
    size_t off_cbase  = align256(off_ctot   + (size_t)NB * 4);
    size_t off_offs   = align256(off_cbase  + (size_t)(NB + 1) * 4);
    size_t off_cpairs = align256(off_offs   + (size_t)(N + 1) * 4);
    size_t off_pairs  = align256(off_cpairs + (size_t)E * 8);
    size_t off_xh     = align256(off_pairs  + (size_t)E * 8);
    size_t off_aggh   = align256(off_xh     + (size_t)N * D * 2);
    size_t off_wt     = align256(off_aggh   + (size_t)N * D * 2);
    size_t need_b     = off_xh;                        // sorted fp32 path
    size_t need_a     = off_wt + (size_t)256 * D * 2;  // full fp16 MFMA path

    const bool fits_meta = (N <= (1 << 20)) && ((N + CSZ - 1) >> CBITS) <= NB;

    if (ws_size >= need_b && fits_meta) {
        char* ws = (char*)d_ws;
        int*  bhist  = (int*) (ws + off_bhist);
        int*  ctot   = (int*) (ws + off_ctot);
        int*  cbase  = (int*) (ws + off_cbase);
        int*  offs   = (int*) (ws + off_offs);
        int2* cpairs = (int2*)(ws + off_cpairs);
        int2* pairs  = (int2*)(ws + off_pairs);
        __half2* xh  = (__half2*)(ws + off_xh);
        __half*  agh = (__half*)(ws + off_aggh);
        __half*  wt  = (__half*)(ws + off_wt);

        const bool mfma = (ws_size >= need_a);
        const int chunk = (E + NPART - 1) / NPART;
        const int nbu = (N + CSZ - 1) >> CBITS;

        if (mfma) {
            cvt_x_fp16<<<4096, 256, 0, stream>>>((const float4*)x, xh, N * (D / 4));
            wt_build<<<128, 256, 0, stream>>>(Wl, Wr, wt);
        }
        coarse_count<<<NPART, 256, 0, stream>>>(edst, bhist, E, chunk);
        bucket_scan<<<NB / 64, 64, 0, stream>>>(bhist, ctot);
        coarse_scan<<<1, NB, 0, stream>>>(ctot, cbase, offs, N, E);
        coarse_partition<<<NPART, 256, 0, stream>>>(esrc, edst, ew, bhist, cbase,
                                                    cpairs, E, chunk);
        fine_sort<<<nbu, 256, 0, stream>>>(cpairs, cbase, offs, pairs, N);

        const int gb = (N * 64 + 255) / 256;   // one wave per node
        const int nb = (N + 63) / 64;
        if (mfma) {
            sage_gather<true ><<<gb, 256, 0, stream>>>(xh, pairs, offs, agh, N);
            sage_linear_norm_mfma<<<nb, 256, 0, stream>>>(agh, (const __half*)xh, wt,
                                                          bl, br, out, N);
        } else {
            sage_gather<false><<<gb, 256, 0, stream>>>(x, pairs, offs, out, N);
            sage_linear_norm<<<nb, 256, 0, stream>>>(out, x, Wl, bl, Wr, br, out, N);
        }
    } else {
        hipMemsetAsync(out, 0, (size_t)N * D * sizeof(float), stream);
        sage_scatter<<<2048, 256, 0, stream>>>(x, esrc, edst, ew, out, E);
        const int nb = (N + 63) / 64;
        sage_linear_norm<<<nb, 256, 0, stream>>>(out, x, Wl, bl, Wr, br, out, N);
    }
}